// Round 11
// baseline (94.349 us; speedup 1.0000x reference)
//
#include <hip/hip_runtime.h>

#define T_DIM 256
#define C_DIM 384
#define H_DIM 64

typedef __attribute__((ext_vector_type(4))) float f32x4;
typedef __attribute__((ext_vector_type(8))) short bf16x8;
typedef unsigned short u16;

// fp32 -> bf16 round-to-nearest-even (finite inputs)
__device__ __forceinline__ u16 f2b(float f) {
  unsigned u = __float_as_uint(f);
  u = (u + 0x7FFFu + ((u >> 16) & 1u)) >> 16;
  return (u16)u;
}
// packed f32x2 -> bf16x2: lo word = bf16(a), hi word = bf16(b)  (HW-verified R7/R8)
__device__ __forceinline__ unsigned pkbf(float a, float b) {
  unsigned r;
  asm("v_cvt_pk_bf16_f32 %0, %1, %2" : "=v"(r) : "v"(a), "v"(b));
  return r;
}

// Swizzled element offsets (u16 units). Writes and reads share the permutation.
__device__ __forceinline__ int sw64(int r, int c)  { return r * 64  + (c ^ ((r & 7) << 3)); }
__device__ __forceinline__ int sw256(int h, int t) { return h * 256 + (t ^ ((h & 7) << 3)); }

// One block per batch. 1024 threads = 16 waves (4 waves/SIMD).
// LAUNCH BOUNDS (empirical, R6/R7/R9/R10): on THIS toolchain the 2nd arg acts
// as min BLOCKS/CU (CUDA semantics): (512,2)->104 VGPR, (512,4)->64,
// (1024,4)->64, (1024,2)->64 (=32 waves/CU cap). With 1024 threads, ANY 2nd
// arg >=2 forces the 64-VGPR clamp -> spill. Use bare (1024): 1 block/CU min
// -> 4 waves/SIMD -> 128-VGPR cap, demand ~115 fits, no spill.
// Phase 1: QKV = x_b @ [Wq|Wk|Wv], M=256 N=192 K=384, K-step 64.
//   A-operand (x rows): DIRECT from global (zero cross-wave reuse -> no LDS),
//   depth-2 register prefetch, barrier-independent.
//   B-operand (W^T):    LDS-staged [192][64] sw64 (16x wave reuse), 12 barriers total.
// Handoff + Phase 2 (swapped-operand flash attention): R8-proven, unchanged.
__global__ __launch_bounds__(1024)
void head_fused(const float* __restrict__ x,
                const float* __restrict__ Wk,
                const float* __restrict__ Wq,
                const float* __restrict__ Wv,
                float* __restrict__ out)
{
  __shared__ u16 sh[32768];   // 64 KB union:
  // phase 1: wsT = sh[0..12288) [192][64] sw64 (24 KB)
  // handoff: per-wave Q slab at sh[wv*1024 .. +1024) [16][64] sw64
  // phase 2: ks = sh[0..16384) [256][64] sw64; vT = sh[16384..32768) [64][256] sw256
  u16* wsT = sh;
  u16* ks  = sh;
  u16* vT  = sh + 16384;

  const int tid  = threadIdx.x;
  const int wv   = tid >> 6;     // 0..15
  const int lane = tid & 63;
  const int g    = lane >> 4;
  const int lr   = lane & 15;
  const int b    = blockIdx.x;

  const float* xb = x + (size_t)b * (T_DIM * C_DIM);
  // this lane's A-row and k-offset: afr[kb][e] = x[row][kt*64 + kb*32 + 8g + e]
  const float* xrow = xb + (wv * 16 + lr) * C_DIM + g * 8;

  // ---------------- Phase 1: QKV projection ----------------
  // W staging: 3 tasks/thread; task it: wave-uniform row-quad (seg=it, hq=wv),
  // col = lane (conflict-free stores).
  const float* wsrc[3];
#pragma unroll
  for (int it = 0; it < 3; ++it) {
    const float* W = (it == 0) ? Wq : (it == 1) ? Wk : Wv;
    wsrc[it] = W + (size_t)lane * H_DIM + wv * 4;   // + kt*64*H_DIM per chunk
  }
  const int wrow0 = wv * 4;   // within segment; wsT row = it*64 + wrow0 + jj

  f32x4 acc[12];
#pragma unroll
  for (int nj = 0; nj < 12; ++nj)
    acc[nj] = (f32x4){0.f, 0.f, 0.f, 0.f};

  // A prefetch, depth 2: pA[parity][4] covers one 64-wide K-chunk
  f32x4 pA[2][4];
  f32x4 pwv[3];
#pragma unroll
  for (int c = 0; c < 2; ++c) {
    const float* p = xrow + c * 64;
    pA[c][0] = *reinterpret_cast<const f32x4*>(p);
    pA[c][1] = *reinterpret_cast<const f32x4*>(p + 4);
    pA[c][2] = *reinterpret_cast<const f32x4*>(p + 32);
    pA[c][3] = *reinterpret_cast<const f32x4*>(p + 36);
  }
#pragma unroll
  for (int it = 0; it < 3; ++it)
    pwv[it] = *reinterpret_cast<const f32x4*>(wsrc[it]);

#pragma unroll
  for (int kt = 0; kt < 6; ++kt) {
    const int c = kt & 1;
    // convert this chunk's A regs -> fragments (register-only, barrier-independent)
    bf16x8 afr[2];
    {
      union { unsigned w[4]; bf16x8 v; } u0, u1;
      u0.w[0] = pkbf(pA[c][0][0], pA[c][0][1]);
      u0.w[1] = pkbf(pA[c][0][2], pA[c][0][3]);
      u0.w[2] = pkbf(pA[c][1][0], pA[c][1][1]);
      u0.w[3] = pkbf(pA[c][1][2], pA[c][1][3]);
      u1.w[0] = pkbf(pA[c][2][0], pA[c][2][1]);
      u1.w[1] = pkbf(pA[c][2][2], pA[c][2][3]);
      u1.w[2] = pkbf(pA[c][3][0], pA[c][3][1]);
      u1.w[3] = pkbf(pA[c][3][2], pA[c][3][3]);
      afr[0] = u0.v; afr[1] = u1.v;
    }
    // issue A loads for chunk kt+2 into the freed parity slot
    if (kt < 4) {
      const float* p = xrow + (kt + 2) * 64;
      pA[c][0] = *reinterpret_cast<const f32x4*>(p);
      pA[c][1] = *reinterpret_cast<const f32x4*>(p + 4);
      pA[c][2] = *reinterpret_cast<const f32x4*>(p + 32);
      pA[c][3] = *reinterpret_cast<const f32x4*>(p + 36);
    }

    __syncthreads();   // previous iteration's wsT reads done
    // stage W chunk kt (lane-consecutive columns -> conflict-free)
#pragma unroll
    for (int it = 0; it < 3; ++it)
#pragma unroll
      for (int jj = 0; jj < 4; ++jj)
        wsT[sw64(it * 64 + wrow0 + jj, lane)] = f2b(pwv[it][jj]);
    // prefetch W chunk kt+1 (L2-resident after first block)
    if (kt < 5) {
#pragma unroll
      for (int it = 0; it < 3; ++it)
        pwv[it] = *reinterpret_cast<const f32x4*>(wsrc[it] + (size_t)(kt + 1) * 64 * H_DIM);
    }
    __syncthreads();

    // MFMA: wave wv computes rows [16wv,16wv+16), all 192 N cols, K=64
#pragma unroll
    for (int nj = 0; nj < 12; ++nj) {
      bf16x8 bfr0 = *reinterpret_cast<const bf16x8*>(&wsT[sw64(nj * 16 + lr, g * 8)]);
      acc[nj] = __builtin_amdgcn_mfma_f32_16x16x32_bf16(afr[0], bfr0, acc[nj], 0, 0, 0);
      bf16x8 bfr1 = *reinterpret_cast<const bf16x8*>(&wsT[sw64(nj * 16 + lr, 32 + g * 8)]);
      acc[nj] = __builtin_amdgcn_mfma_f32_16x16x32_bf16(afr[1], bfr1, acc[nj], 0, 0, 0);
    }
  }

  // ---------------- Handoff (R8-proven) ----------------
  __syncthreads();   // all wsT reads done; region now dead

  // (1) own Q rows D->slab (acc nj 0..3 hold Q[16wv + 4g+e][16nj+lr])
  u16* slab = sh + wv * 1024;   // [16][64] sw64, wave-private
#pragma unroll
  for (int nj = 0; nj < 4; ++nj)
#pragma unroll
    for (int e = 0; e < 4; ++e)
      slab[sw64(g * 4 + e, nj * 16 + lr)] = f2b(acc[nj][e]);
  asm volatile("s_waitcnt lgkmcnt(0)" ::: "memory");

  // (2) read Q as B-fragments: qf[kb][e] = Q[16wv+lr][32kb+8g+e]
  bf16x8 qf[2];
#pragma unroll
  for (int kb = 0; kb < 2; ++kb)
    qf[kb] = *reinterpret_cast<const bf16x8*>(&slab[sw64(lr, kb * 32 + g * 8)]);
  __syncthreads();   // all slab reads done before K/V scatter overwrites region

  // (3) scatter K,V fragments (acc nj 4..11) into ks/vT
#pragma unroll
  for (int nj = 4; nj < 12; ++nj)
#pragma unroll
    for (int e = 0; e < 4; ++e) {
      int r = wv * 16 + g * 4 + e;
      int n = nj * 16 + lr;
      u16 val = f2b(acc[nj][e]);
      if (n < 128) ks[sw64(r, n - 64)] = val;
      else         vT[sw256(n - 128, r)] = val;
    }
  __syncthreads();

  // ---------------- Phase 2: swapped-operand causal flash attention (R8-proven) ----------------
  const int r0   = wv * 16;
  const int jmax = wv >> 2;   // per-SIMD tile totals balanced

  f32x4 o[4];                 // O D-layout: row q-local = 4g+e, col h = 16nh+lr
  float m_run = -__builtin_inff(), l_run = 0.f;   // per-lane stats for q = r0+lr
#pragma unroll
  for (int nh = 0; nh < 4; ++nh) o[nh] = (f32x4){0.f, 0.f, 0.f, 0.f};

  for (int j = 0; j <= jmax; ++j) {
    // S^T tile: sT[ni][e] = S[q = r0+lr][kv = 64j+16ni+4g+e]
    f32x4 sT[4];
#pragma unroll
    for (int ni = 0; ni < 4; ++ni) sT[ni] = (f32x4){0.f, 0.f, 0.f, 0.f};
#pragma unroll
    for (int kb = 0; kb < 2; ++kb) {
#pragma unroll
      for (int ni = 0; ni < 4; ++ni) {
        bf16x8 kf = *reinterpret_cast<const bf16x8*>(&ks[sw64(j * 64 + ni * 16 + lr, kb * 32 + g * 8)]);
        sT[ni] = __builtin_amdgcn_mfma_f32_16x16x32_bf16(kf, qf[kb], sT[ni], 0, 0, 0);
      }
    }

    // scale + causal mask + per-lane-q softmax
    const int q = r0 + lr;
    float pm = -__builtin_inff();
#pragma unroll
    for (int ni = 0; ni < 4; ++ni)
#pragma unroll
      for (int e = 0; e < 4; ++e) {
        float v = sT[ni][e] * 0.125f;
        int kv = j * 64 + ni * 16 + g * 4 + e;
        v = (kv > q) ? -__builtin_inff() : v;
        sT[ni][e] = v;
        pm = fmaxf(pm, v);
      }
    pm = fmaxf(pm, __shfl_xor(pm, 16));
    pm = fmaxf(pm, __shfl_xor(pm, 32));

    float mn = fmaxf(m_run, pm);
    float alpha = __expf(m_run - mn);   // first tile: exp(-inf)=0
    m_run = mn;
    float rs = 0.f;
#pragma unroll
    for (int ni = 0; ni < 4; ++ni)
#pragma unroll
      for (int e = 0; e < 4; ++e) {
        float p = __expf(sT[ni][e] - mn);  // masked: exp(-inf)=0
        sT[ni][e] = p;
        rs += p;
      }
    rs += __shfl_xor(rs, 16);
    rs += __shfl_xor(rs, 32);
    l_run = l_run * alpha + rs;

    // rescale O (alpha for q-row 4g+e lives at lane 4g+e within the 16-group)
#pragma unroll
    for (int e = 0; e < 4; ++e) {
      float am = __shfl(alpha, g * 4 + e);
#pragma unroll
      for (int nh = 0; nh < 4; ++nh) o[nh][e] *= am;
    }

    // P D->A transpose via g-group shfl exchange (R7/R8-proven map)
    union PA { unsigned w[4]; bf16x8 v; };
    PA pa[2];
    unsigned pk[4][2];
#pragma unroll
    for (int ni = 0; ni < 4; ++ni) {
      pk[ni][0] = pkbf(sT[ni][0], sT[ni][1]);  // kv {16ni+4g+0, +1}
      pk[ni][1] = pkbf(sT[ni][2], sT[ni][3]);  // kv {16ni+4g+2, +3}
    }
#pragma unroll
    for (int kb = 0; kb < 2; ++kb)
#pragma unroll
      for (int w = 0; w < 4; ++w) {
        int sl = ((2 * g + (w >> 1)) & 3) * 16 + lr;   // source lane
        unsigned lo = __shfl(pk[2 * kb + 0][w & 1], sl);
        unsigned hi = __shfl(pk[2 * kb + 1][w & 1], sl);
        pa[kb].w[w] = (g >= 2) ? hi : lo;
      }

    // O += P @ V_tile
#pragma unroll
    for (int kb = 0; kb < 2; ++kb) {
#pragma unroll
      for (int nh = 0; nh < 4; ++nh) {
        bf16x8 vf = *reinterpret_cast<const bf16x8*>(&vT[sw256(nh * 16 + lr, j * 64 + kb * 32 + g * 8)]);
        o[nh] = __builtin_amdgcn_mfma_f32_16x16x32_bf16(pa[kb].v, vf, o[nh], 0, 0, 0);
      }
    }
  }

  // epilogue: normalize and store fp32 (l for q-row 4g+e lives at lane 4g+e)
  float* ob = out + (size_t)b * (T_DIM * H_DIM);
  float linv[4];
#pragma unroll
  for (int e = 0; e < 4; ++e)
    linv[e] = 1.f / __shfl(l_run, g * 4 + e);
#pragma unroll
  for (int nh = 0; nh < 4; ++nh)
#pragma unroll
    for (int e = 0; e < 4; ++e) {
      int r = r0 + g * 4 + e;
      int h = nh * 16 + lr;
      ob[r * H_DIM + h] = o[nh][e] * linv[e];
    }
}

extern "C" void kernel_launch(void* const* d_in, const int* in_sizes, int n_in,
                              void* d_out, int out_size, void* d_ws, size_t ws_size,
                              hipStream_t stream) {
  const float* x  = (const float*)d_in[0];
  const float* Wk = (const float*)d_in[1];
  const float* Wq = (const float*)d_in[2];
  const float* Wv = (const float*)d_in[3];
  float* out = (float*)d_out;
  int B = in_sizes[0] / (T_DIM * C_DIM);   // 512
  head_fused<<<dim3(B), dim3(1024), 0, stream>>>(x, Wk, Wq, Wv, out);
}

// Round 12
// 62.757 us; speedup vs baseline: 1.5034x; 1.5034x over previous
//
#include <hip/hip_runtime.h>

#define T_DIM 256
#define C_DIM 384
#define H_DIM 64

typedef __attribute__((ext_vector_type(4))) float f32x4;
typedef __attribute__((ext_vector_type(8))) short bf16x8;
typedef unsigned short u16;

// fp32 -> bf16 round-to-nearest-even (finite inputs)
__device__ __forceinline__ u16 f2b(float f) {
  unsigned u = __float_as_uint(f);
  u = (u + 0x7FFFu + ((u >> 16) & 1u)) >> 16;
  return (u16)u;
}
// packed f32x2 -> bf16x2: lo word = bf16(a), hi word = bf16(b)  (HW-verified R7/R8)
__device__ __forceinline__ unsigned pkbf(float a, float b) {
  unsigned r;
  asm("v_cvt_pk_bf16_f32 %0, %1, %2" : "=v"(r) : "v"(a), "v"(b));
  return r;
}

// Swizzled element offsets (u16 units). Writes and reads share the permutation.
__device__ __forceinline__ int sw64(int r, int c)  { return r * 64  + (c ^ ((r & 7) << 3)); }
__device__ __forceinline__ int sw256(int h, int t) { return h * 256 + (t ^ ((h & 7) << 3)); }
__device__ __forceinline__ int sw32(int r, int c)  { return r * 32  + (c ^ (((r >> 1) & 3) << 3)); }

// One block per batch. 512 threads = 8 waves. LDS = 64 KB -> 2 blocks/CU.
// LAUNCH-BOUNDS LAW (empirical R6-R11): 1024-thr blocks always clamp to 64 VGPR
// (spill); 512-thr: (512,2) -> cap 128 (R6 allocated 104, clean), (512,4) ->
// cap 64 (R7 spilled). This kernel = R7's correctness-proven source with the
// single fix (512,4) -> (512,2): same structure, no spill, 2 blocks/CU so one
// block's phase-2 compute overlaps the other's phase-1 HBM staging.
// Phase 1: QKV = x_b @ [Wq|Wk|Wv], M=256 N=192 K=384, K-step 32 (R6-proven).
// Handoff: per-wave Q D->B transpose through a private slab in dead staging LDS.
// Phase 2: swapped-operand flash attention: S^T = mfma(K, Q) makes q lane-local;
// softmax reduce = 2 shfls; P D->A transpose = g-group shfl exchange (no LDS).
__global__ __launch_bounds__(512, 2)
void head_fused(const float* __restrict__ x,
                const float* __restrict__ Wk,
                const float* __restrict__ Wq,
                const float* __restrict__ Wv,
                float* __restrict__ out)
{
  __shared__ u16 sh[32768];   // 64 KB union:
  // phase 1: xs = sh[0..8192) [256][32] sw32; wsT = sh[8192..14336) [192][32] sw32
  // handoff: per-wave Q slab at sh[wv*2048 .. +2048) [32][64] sw64
  // phase 2: ks = sh[0..16384) [256][64] sw64; vT = sh[16384..32768) [64][256] sw256
  u16* xs  = sh;
  u16* wsT = sh + 8192;
  u16* ks  = sh;
  u16* vT  = sh + 16384;

  const int tid  = threadIdx.x;
  const int wv   = tid >> 6;
  const int lane = tid & 63;
  const int g    = lane >> 4;
  const int lr   = lane & 15;
  const int b    = blockIdx.x;

  const float* xb = x + (size_t)b * (T_DIM * C_DIM);

  // ---------------- Phase 1: QKV projection (R6 verbatim) ----------------
  int xr[4], xc[4];
#pragma unroll
  for (int it = 0; it < 4; ++it) {
    int idx = tid + it * 512;
    xr[it] = idx >> 3;
    xc[it] = (idx & 7) * 4;
  }
  int wrow[3], wcc[3];
  const float* wsrc[3];
#pragma unroll
  for (int it = 0; it < 3; ++it) {
    int idx = tid + it * 512;          // 0..1535
    int q   = idx >> 5;                // row-quad 0..47
    int cc  = idx & 31;                // col 0..31
    int seg = q >> 4;                  // 0:Q 1:K 2:V
    int hq  = q & 15;
    wrow[it] = seg * 64 + hq * 4;
    wcc[it]  = cc;
    wsrc[it] = ((seg == 0) ? Wq : (seg == 1) ? Wk : Wv) + hq * 4;
  }

  f32x4 acc[2][12];
#pragma unroll
  for (int mi = 0; mi < 2; ++mi)
#pragma unroll
    for (int nj = 0; nj < 12; ++nj)
      acc[mi][nj] = (f32x4){0.f, 0.f, 0.f, 0.f};

  f32x4 px[4], pwv[3];
#pragma unroll
  for (int it = 0; it < 4; ++it)
    px[it] = *reinterpret_cast<const f32x4*>(xb + xr[it] * C_DIM + xc[it]);
#pragma unroll
  for (int it = 0; it < 3; ++it)
    pwv[it] = *reinterpret_cast<const f32x4*>(wsrc[it] + wcc[it] * H_DIM);

  for (int kt = 0; kt < 12; ++kt) {
    __syncthreads();
#pragma unroll
    for (int it = 0; it < 4; ++it) {
      uint2 pv;
      pv.x = (unsigned)f2b(px[it][0]) | ((unsigned)f2b(px[it][1]) << 16);
      pv.y = (unsigned)f2b(px[it][2]) | ((unsigned)f2b(px[it][3]) << 16);
      *reinterpret_cast<uint2*>(&xs[sw32(xr[it], xc[it])]) = pv;
    }
#pragma unroll
    for (int it = 0; it < 3; ++it) {
      wsT[sw32(wrow[it] + 0, wcc[it])] = f2b(pwv[it][0]);
      wsT[sw32(wrow[it] + 1, wcc[it])] = f2b(pwv[it][1]);
      wsT[sw32(wrow[it] + 2, wcc[it])] = f2b(pwv[it][2]);
      wsT[sw32(wrow[it] + 3, wcc[it])] = f2b(pwv[it][3]);
    }
    if (kt < 11) {
      int kk = (kt + 1) * 32;
#pragma unroll
      for (int it = 0; it < 4; ++it)
        px[it] = *reinterpret_cast<const f32x4*>(xb + xr[it] * C_DIM + kk + xc[it]);
#pragma unroll
      for (int it = 0; it < 3; ++it)
        pwv[it] = *reinterpret_cast<const f32x4*>(wsrc[it] + (kk + wcc[it]) * H_DIM);
    }
    __syncthreads();

    bf16x8 afr[2];
#pragma unroll
    for (int mi = 0; mi < 2; ++mi)
      afr[mi] = *reinterpret_cast<const bf16x8*>(&xs[sw32(wv * 32 + mi * 16 + lr, g * 8)]);
#pragma unroll
    for (int nj = 0; nj < 12; ++nj) {
      bf16x8 bfr = *reinterpret_cast<const bf16x8*>(&wsT[sw32(nj * 16 + lr, g * 8)]);
#pragma unroll
      for (int mi = 0; mi < 2; ++mi)
        acc[mi][nj] = __builtin_amdgcn_mfma_f32_16x16x32_bf16(afr[mi], bfr, acc[mi][nj], 0, 0, 0);
    }
  }

  // ---------------- Handoff (R7-proven) ----------------
  __syncthreads();   // all waves' staging reads done; staging region now dead

  // (1) own Q rows D->slab (acc nj 0..3 hold Q[32wv + 16mi + 4g+e][16nj+lr])
  u16* slab = sh + wv * 2048;   // [32][64] sw64, wave-private
#pragma unroll
  for (int mi = 0; mi < 2; ++mi)
#pragma unroll
    for (int nj = 0; nj < 4; ++nj)
#pragma unroll
      for (int e = 0; e < 4; ++e)
        slab[sw64(mi * 16 + g * 4 + e, nj * 16 + lr)] = f2b(acc[mi][nj][e]);
  asm volatile("s_waitcnt lgkmcnt(0)" ::: "memory");

  // (2) read Q as B-fragments: qf[mi][kb][e] = Q[32wv+16mi+lr][32kb+8g+e]
  bf16x8 qf[2][2];
#pragma unroll
  for (int mi = 0; mi < 2; ++mi)
#pragma unroll
    for (int kb = 0; kb < 2; ++kb)
      qf[mi][kb] = *reinterpret_cast<const bf16x8*>(&slab[sw64(mi * 16 + lr, kb * 32 + g * 8)]);
  __syncthreads();   // all slab reads done before K/V scatter overwrites the region

  // (3) scatter K,V fragments (acc nj 4..11) into ks/vT
#pragma unroll
  for (int mi = 0; mi < 2; ++mi)
#pragma unroll
    for (int nj = 4; nj < 12; ++nj)
#pragma unroll
      for (int e = 0; e < 4; ++e) {
        int r = wv * 32 + mi * 16 + g * 4 + e;
        int n = nj * 16 + lr;
        u16 val = f2b(acc[mi][nj][e]);
        if (n < 128) ks[sw64(r, n - 64)] = val;
        else         vT[sw256(n - 128, r)] = val;
      }
  __syncthreads();

  // ---------------- Phase 2: swapped-operand causal flash attention (R7-proven) ----------------
  const int r0   = wv * 32;
  const int jmax = wv >> 1;

  f32x4 o[2][4];              // O D-layout: row q-local = 16mi+4g+e, col h = 16nh+lr
  float m_run[2], l_run[2];   // per-lane stats for q = r0 + 16mi + lr
#pragma unroll
  for (int mi = 0; mi < 2; ++mi) {
    m_run[mi] = -__builtin_inff();
    l_run[mi] = 0.f;
#pragma unroll
    for (int nh = 0; nh < 4; ++nh) o[mi][nh] = (f32x4){0.f, 0.f, 0.f, 0.f};
  }

  for (int j = 0; j <= jmax; ++j) {
    // S^T tile: sT[mi][ni][e] = S[q = r0+16mi+lr][kv = 64j+16ni+4g+e]
    f32x4 sT[2][4];
#pragma unroll
    for (int mi = 0; mi < 2; ++mi)
#pragma unroll
      for (int ni = 0; ni < 4; ++ni)
        sT[mi][ni] = (f32x4){0.f, 0.f, 0.f, 0.f};
#pragma unroll
    for (int kb = 0; kb < 2; ++kb) {
#pragma unroll
      for (int ni = 0; ni < 4; ++ni) {
        bf16x8 kf = *reinterpret_cast<const bf16x8*>(&ks[sw64(j * 64 + ni * 16 + lr, kb * 32 + g * 8)]);
#pragma unroll
        for (int mi = 0; mi < 2; ++mi)
          sT[mi][ni] = __builtin_amdgcn_mfma_f32_16x16x32_bf16(kf, qf[mi][kb], sT[mi][ni], 0, 0, 0);
      }
    }

    // scale + causal mask + per-row (=per-lane-q) softmax
#pragma unroll
    for (int mi = 0; mi < 2; ++mi) {
      const int q = r0 + mi * 16 + lr;
      float pm = -__builtin_inff();
#pragma unroll
      for (int ni = 0; ni < 4; ++ni)
#pragma unroll
        for (int e = 0; e < 4; ++e) {
          float v = sT[mi][ni][e] * 0.125f;
          int kv = j * 64 + ni * 16 + g * 4 + e;
          v = (kv > q) ? -__builtin_inff() : v;
          sT[mi][ni][e] = v;
          pm = fmaxf(pm, v);
        }
      pm = fmaxf(pm, __shfl_xor(pm, 16));
      pm = fmaxf(pm, __shfl_xor(pm, 32));

      float mn = fmaxf(m_run[mi], pm);
      float alpha = __expf(m_run[mi] - mn);   // first tile: exp(-inf)=0
      m_run[mi] = mn;
      float rs = 0.f;
#pragma unroll
      for (int ni = 0; ni < 4; ++ni)
#pragma unroll
        for (int e = 0; e < 4; ++e) {
          float p = __expf(sT[mi][ni][e] - mn);  // masked: exp(-inf)=0
          sT[mi][ni][e] = p;
          rs += p;
        }
      rs += __shfl_xor(rs, 16);
      rs += __shfl_xor(rs, 32);
      l_run[mi] = l_run[mi] * alpha + rs;

      // rescale O (alpha for q-row 16mi+4g+e lives at lane lr' = 4g+e)
#pragma unroll
      for (int e = 0; e < 4; ++e) {
        float am = __shfl(alpha, g * 4 + e);
#pragma unroll
        for (int nh = 0; nh < 4; ++nh) o[mi][nh][e] *= am;
      }
    }

    // P D->A transpose via g-group exchange (no LDS)
    union PA { unsigned w[4]; bf16x8 v; };
    PA pa[2][2];
#pragma unroll
    for (int mi = 0; mi < 2; ++mi) {
      unsigned pk[4][2];
#pragma unroll
      for (int ni = 0; ni < 4; ++ni) {
        pk[ni][0] = pkbf(sT[mi][ni][0], sT[mi][ni][1]);  // kv {16ni+4g+0, +1}
        pk[ni][1] = pkbf(sT[mi][ni][2], sT[mi][ni][3]);  // kv {16ni+4g+2, +3}
      }
#pragma unroll
      for (int kb = 0; kb < 2; ++kb)
#pragma unroll
        for (int w = 0; w < 4; ++w) {
          int sl = ((2 * g + (w >> 1)) & 3) * 16 + lr;   // source lane
          unsigned lo = __shfl(pk[2 * kb + 0][w & 1], sl);
          unsigned hi = __shfl(pk[2 * kb + 1][w & 1], sl);
          pa[mi][kb].w[w] = (g >= 2) ? hi : lo;
        }
    }

    // O += P @ V_tile
#pragma unroll
    for (int kb = 0; kb < 2; ++kb) {
#pragma unroll
      for (int nh = 0; nh < 4; ++nh) {
        bf16x8 vf = *reinterpret_cast<const bf16x8*>(&vT[sw256(nh * 16 + lr, j * 64 + kb * 32 + g * 8)]);
#pragma unroll
        for (int mi = 0; mi < 2; ++mi)
          o[mi][nh] = __builtin_amdgcn_mfma_f32_16x16x32_bf16(pa[mi][kb].v, vf, o[mi][nh], 0, 0, 0);
      }
    }
  }

  // epilogue: normalize and store fp32 (l for q-row 16mi+4g+e lives at lane 4g+e)
  float* ob = out + (size_t)b * (T_DIM * H_DIM);
#pragma unroll
  for (int mi = 0; mi < 2; ++mi) {
    float linv[4];
#pragma unroll
    for (int e = 0; e < 4; ++e)
      linv[e] = 1.f / __shfl(l_run[mi], g * 4 + e);
#pragma unroll
    for (int nh = 0; nh < 4; ++nh)
#pragma unroll
      for (int e = 0; e < 4; ++e) {
        int r = r0 + mi * 16 + g * 4 + e;
        int h = nh * 16 + lr;
        ob[r * H_DIM + h] = o[mi][nh][e] * linv[e];
      }
  }
}

extern "C" void kernel_launch(void* const* d_in, const int* in_sizes, int n_in,
                              void* d_out, int out_size, void* d_ws, size_t ws_size,
                              hipStream_t stream) {
  const float* x  = (const float*)d_in[0];
  const float* Wk = (const float*)d_in[1];
  const float* Wq = (const float*)d_in[2];
  const float* Wv = (const float*)d_in[3];
  float* out = (float*)d_out;
  int B = in_sizes[0] / (T_DIM * C_DIM);   // 512
  head_fused<<<dim3(B), dim3(512), 0, stream>>>(x, Wk, Wq, Wv, out);
}